// Round 5
// baseline (726.767 us; speedup 1.0000x reference)
//
#include <hip/hip_runtime.h>
#include <cstdint>
#include <cstddef>

#define BB 1024
#define AA 200
#define DD 128
#define HH 8
#define N3 384

typedef unsigned short u16;
typedef unsigned int u32;
typedef __attribute__((ext_vector_type(8))) short bf16x8;
typedef __attribute__((ext_vector_type(4))) float f32x4;

__device__ __forceinline__ float bf2f(u16 v){ return __uint_as_float(((u32)v) << 16); }
__device__ __forceinline__ u16 f2bf(float f){
  u32 u = __float_as_uint(f);
  u32 r = u + 0x7fffu + ((u >> 16) & 1u);
  return (u16)(r >> 16);
}
// RNE pair pack (pure C)
__device__ __forceinline__ u32 pack2(float lo, float hi){
  return (u32)f2bf(lo) | ((u32)f2bf(hi) << 16);
}
// truncating pair pack (3 VALU ops) — used for P e-values only (round-0-verified)
__device__ __forceinline__ u32 pack2t(float lo, float hi){
  return (__float_as_uint(hi) & 0xFFFF0000u) | (__float_as_uint(lo) >> 16);
}
__device__ __forceinline__ bf16x8 pack8(float4 a, float4 b){
  bf16x8 o;
  o[0] = (short)f2bf(a.x); o[1] = (short)f2bf(a.y);
  o[2] = (short)f2bf(a.z); o[3] = (short)f2bf(a.w);
  o[4] = (short)f2bf(b.x); o[5] = (short)f2bf(b.y);
  o[6] = (short)f2bf(b.z); o[7] = (short)f2bf(b.w);
  return o;
}

// ---------------- K0: copy old_action to out (as float) + build rank ----------------
__global__ void k_act_rank(const int* __restrict__ oa, float* __restrict__ out0,
                           int* __restrict__ rank){
  int m = blockIdx.x * 256 + threadIdx.x;
  if (m >= BB*AA) return;
  int v = oa[m];
  out0[m] = (float)v;
  int b = m / AA;
  int j = m - b*AA;
  rank[b*AA + v] = j;
}

// ---------------- K0b: transpose+cast weights to bf16 [n][k] ----------------
__global__ void k_prep(const float* __restrict__ Wn, const float* __restrict__ Ws,
                       const float* __restrict__ Wo,
                       u16* __restrict__ WnT, u16* __restrict__ WsT,
                       u16* __restrict__ WoT){
  int idx = blockIdx.x * 256 + threadIdx.x;
  if (idx < 49152){                       // WnT: [384][128]
    int n = idx >> 7, k = idx & 127;
    WnT[idx] = f2bf(Wn[k*N3 + n]);
  } else if (idx < 65536){                // WsT: [128][128]
    int j = idx - 49152;
    int n = j >> 7, k = j & 127;
    WsT[j] = f2bf(Ws[k*DD + n]);
  } else if (idx < 81920){                // WoT: [128][128]
    int j = idx - 65536;
    int n = j >> 7, k = j & 127;
    WoT[j] = f2bf(Wo[k*DD + n]);
  }
}

// ---------------- K1: fixed_ctx = mean_a(E[b]) @ W_fixed ----------------
// 256 threads: two 100-row half-sums (halved dep chain, 2x TLP), LDS combine, GEMV.
__global__ void k_fixed(const float* __restrict__ E, const float* __restrict__ Wf,
                        float* __restrict__ fixedc){
  int b = blockIdx.x;
  int t = threadIdx.x;              // 256 threads
  int half = t >> 7, d = t & 127;
  __shared__ float ge[2][DD];
  const float* Eb = E + (size_t)b*AA*DD + (size_t)half*100*DD;
  float s = 0.f;
  #pragma unroll 4
  for (int a = 0; a < 100; ++a) s += Eb[a*DD + d];
  ge[half][d] = s;
  __syncthreads();
  if (t < DD){
    float g = (ge[0][t] + ge[1][t]) * (1.0f/AA);
    float acc = 0.f;
    for (int k = 0; k < DD; ++k){
      float gk = (ge[0][k] + ge[1][k]) * (1.0f/AA);
      acc = fmaf(gk, Wf[k*DD + t], acc);
    }
    (void)g;
    fixedc[b*DD + t] = acc;
  }
}

// ---------------- K2a: proj = E @ W_node via MFMA, swapped operands ----------------
// A = WnT rows (n), B = E rows (m) -> D: lane l16 = m-row, regs = 4 consecutive n.
// Each wave: 16 rows x all 384 cols in 3 chunks of 128 (acc 8 tiles/chunk).
// E fetched from HBM once (chunks re-read from L1); stores are 8B uint2.
__global__ __launch_bounds__(256) void k_proj_mfma(const float* __restrict__ E,
                                                   const u16* __restrict__ WnT,
                                                   u16* __restrict__ proj){
  const int t = threadIdx.x;
  const int w = t >> 6, L = t & 63;
  const int l16 = L & 15, lq = L >> 4;
  const int row = blockIdx.x * 64 + w*16 + l16;    // wave covers 16 rows
  const float* Erow = E + (size_t)row*DD;
  u16* dst = proj + (size_t)row*N3;

  #pragma unroll
  for (int c = 0; c < 3; ++c){
    const int n0 = c*128;
    f32x4 acc[8] = {};
    #pragma unroll
    for (int ks = 0; ks < 4; ++ks){
      int ko = ks*32 + lq*8;
      bf16x8 bfrag = pack8(*(const float4*)(Erow + ko), *(const float4*)(Erow + ko + 4));
      #pragma unroll
      for (int nt = 0; nt < 8; ++nt){
        union { uint4 u; bf16x8 v; } aa;
        aa.u = *(const uint4*)(WnT + (size_t)(n0 + nt*16 + l16)*DD + ko);
        acc[nt] = __builtin_amdgcn_mfma_f32_16x16x32_bf16(aa.v, bfrag, acc[nt], 0, 0, 0);
      }
    }
    // lane (l16, lq) holds D[n = n0+nt*16+lq*4+r][m = row(l16)] -> 8B store per nt
    #pragma unroll
    for (int nt = 0; nt < 8; ++nt){
      uint2 ov;
      ov.x = pack2(acc[nt][0], acc[nt][1]);
      ov.y = pack2(acc[nt][2], acc[nt][3]);
      *(uint2*)(dst + n0 + nt*16 + lq*4) = ov;
    }
  }
}

// ---------------- K2b: query = (fixed_ctx + gather(E,prev) @ W_step) * 0.25 via MFMA ----------------
// NOTE: 1/sqrt(dh)=0.25 folded into the stored query (qhg consumed only by k_attn QK^T).
__global__ __launch_bounds__(256) void k_query_mfma(const float* __restrict__ E,
                                                    const int* __restrict__ oa,
                                                    const float* __restrict__ Wp,
                                                    const u16* __restrict__ WsT,
                                                    const float* __restrict__ fixedc,
                                                    u16* __restrict__ qhg){
  const int t = threadIdx.x;
  const int w = t >> 6, L = t & 63;
  const int l16 = L & 15, lq = L >> 4;
  const int m0 = blockIdx.x * 128;
  const int row0 = m0 + w*32;

  const float* src[2];
  #pragma unroll
  for (int mt = 0; mt < 2; ++mt){
    int q = row0 + mt*16 + l16;
    int b = q / AA, i = q - b*AA;
    src[mt] = (i == 0) ? Wp : (E + (size_t)(b*AA + oa[b*AA + i - 1])*DD);
  }

  f32x4 acc[2][8] = {};
  #pragma unroll
  for (int ks = 0; ks < 4; ++ks){
    int ko = ks*32 + lq*8;
    bf16x8 a0 = pack8(*(const float4*)(src[0] + ko), *(const float4*)(src[0] + ko + 4));
    bf16x8 a1 = pack8(*(const float4*)(src[1] + ko), *(const float4*)(src[1] + ko + 4));
    #pragma unroll
    for (int nt = 0; nt < 8; ++nt){
      union { uint4 u; bf16x8 v; } bb;
      bb.u = *(const uint4*)(WsT + (size_t)(nt*16 + l16)*DD + ko);
      acc[0][nt] = __builtin_amdgcn_mfma_f32_16x16x32_bf16(a0, bb.v, acc[0][nt], 0, 0, 0);
      acc[1][nt] = __builtin_amdgcn_mfma_f32_16x16x32_bf16(a1, bb.v, acc[1][nt], 0, 0, 0);
    }
  }
  #pragma unroll
  for (int mt = 0; mt < 2; ++mt)
    #pragma unroll
    for (int r = 0; r < 4; ++r){
      int row = row0 + mt*16 + lq*4 + r;
      int b = row / AA;
      const float* fc = fixedc + (size_t)b*DD;
      u16* dst = qhg + (size_t)row*DD;
      #pragma unroll
      for (int nt = 0; nt < 8; ++nt)
        dst[nt*16 + l16] = f2bf((acc[mt][nt][r] + fc[nt*16 + l16]) * 0.25f);
    }
}

// ---------------- K3: MFMA attention, rank-permuted K/V (triangular mask) ----------------
// LDS row j holds K[old_action[j]] / V[old_action[j]]  (rank[old_action[j]] = j), so
// the revisit mask "rank[a] < i" becomes "j < i":
//   at-tile < it-tile  -> fully masked -> SKIPPED (never computed)
//   at-tile > it-tile  -> fully unmasked -> no mask ops at all
//   at == it (diagonal)-> mask iff (lq*4+r) < l16 (pure lane arith, hoisted compares)
//   at == 12           -> pad rows j>=200 masked via lq>=2
// S^T = mfma(K,Q): lane l16 = i, regs (k,r) hold j = at*16 + lq*4 + r.
// P^T packed on-the-fly (truncating bf16) feeds PV: H^T = V^T P^T.
// Per-wave STATIC tile schedule (compile-time indexing; weight 13-it):
//   w0:{0,3}=23  w1:{1,2}=23  w2:{4,6,8,10,12}=25  w3:{5,7,9,11}=20
#define KSTR 24    // u16 stride for KL rows (bank stagger)
#define VSTR 232   // u16 stride for VT rows
template<int IT>
__device__ __forceinline__ void attn_tile(const u16* KL, const u16* VT,
                                          u16* Qbase, int l16, int lq,
                                          bool dm0, bool dm1, bool dm2, bool dm3){
  constexpr int NT = 13 - IT;
  const int qi = IT*16 + l16;
  const float NEG_INF = -__builtin_inff();

  // B-frag: Q[i=l16][d = lq*4 + j] at elements j=0..3, elements 4..7 zero
  union { uint4 u; bf16x8 v; } qf8;
  qf8.u.x = 0; qf8.u.y = 0; qf8.u.z = 0; qf8.u.w = 0;
  if (qi < AA){
    uint2 q2 = *(const uint2*)(Qbase + (size_t)qi*DD + lq*4);
    qf8.u.x = q2.x; qf8.u.y = q2.y;
  }

  // S^T tiles for at = IT..12 only (at < IT fully masked -> skipped)
  f32x4 S[NT];
  #pragma unroll
  for (int k = 0; k < NT; ++k){
    const int at = IT + k;
    union { uint4 u; bf16x8 v; } kf8;
    uint2 k2 = *(const uint2*)&KL[(at*16 + l16)*KSTR + lq*4];
    kf8.u.x = k2.x; kf8.u.y = k2.y; kf8.u.z = 0; kf8.u.w = 0;
    f32x4 z = {0.f,0.f,0.f,0.f};
    S[k] = __builtin_amdgcn_mfma_f32_16x16x32_bf16(kf8.v, qf8.v, z, 0, 0, 0);
  }
  // diagonal mask (k==0): j < i  <=>  (lq*4+r) < l16
  S[0][0] = dm0 ? NEG_INF : S[0][0];
  S[0][1] = dm1 ? NEG_INF : S[0][1];
  S[0][2] = dm2 ? NEG_INF : S[0][2];
  S[0][3] = dm3 ? NEG_INF : S[0][3];
  // pad mask (at==12 tile is k==NT-1): j = 192 + lq*4 + r >= 200  <=>  lq >= 2
  if (lq >= 2){
    S[NT-1][0] = NEG_INF; S[NT-1][1] = NEG_INF;
    S[NT-1][2] = NEG_INF; S[NT-1][3] = NEG_INF;
  }
  // row max: within-lane + 2 shuffles; clamp so fully-masked pad rows give e=0 not NaN
  float m = fmaxf(fmaxf(S[0][0], S[0][1]), fmaxf(S[0][2], S[0][3]));
  #pragma unroll
  for (int k = 1; k < NT; ++k)
    m = fmaxf(m, fmaxf(fmaxf(S[k][0], S[k][1]), fmaxf(S[k][2], S[k][3])));
  m = fmaxf(m, __shfl_xor(m, 16));
  m = fmaxf(m, __shfl_xor(m, 32));
  m = fmaxf(m, -1e30f);
  // e = exp(S - m); 4 parallel sum chains
  float s0 = 0.f, s1 = 0.f, s2 = 0.f, s3 = 0.f;
  #pragma unroll
  for (int k = 0; k < NT; ++k){
    float e0 = __expf(S[k][0] - m);
    float e1 = __expf(S[k][1] - m);
    float e2 = __expf(S[k][2] - m);
    float e3 = __expf(S[k][3] - m);
    S[k][0] = e0; S[k][1] = e1; S[k][2] = e2; S[k][3] = e3;
    s0 += e0; s1 += e1; s2 += e2; s3 += e3;
  }
  float sum = (s0 + s1) + (s2 + s3);
  sum += __shfl_xor(sum, 16);
  sum += __shfl_xor(sum, 32);
  float inv = 1.0f / sum;
  // H^T = V^T P^T over unmasked j-tiles only
  f32x4 acc = {0.f,0.f,0.f,0.f};
  #pragma unroll
  for (int k = 0; k < NT; ++k){
    const int at = IT + k;
    union { uint4 u; bf16x8 v; } pa8, vb8;
    pa8.u.x = pack2t(S[k][0], S[k][1]);
    pa8.u.y = pack2t(S[k][2], S[k][3]);
    pa8.u.z = 0; pa8.u.w = 0;
    uint2 v2 = *(const uint2*)&VT[l16*VSTR + at*16 + lq*4];
    vb8.u.x = v2.x; vb8.u.y = v2.y; vb8.u.z = 0; vb8.u.w = 0;
    acc = __builtin_amdgcn_mfma_f32_16x16x32_bf16(vb8.v, pa8.v, acc, 0, 0, 0);
  }
  // D: lane holds col i = l16, rows d = lq*4 + r -> H[i][d], packed 8B store (RNE)
  if (qi < AA){
    uint2 ov;
    ov.x = pack2(acc[0]*inv, acc[1]*inv);
    ov.y = pack2(acc[2]*inv, acc[3]*inv);
    *(uint2*)(Qbase + (size_t)qi*DD + lq*4) = ov;
  }
}

__global__ __launch_bounds__(256) void k_attn(const u16* __restrict__ proj,
                                              const int* __restrict__ oa,
                                              u16* __restrict__ qhg){
  __shared__ __align__(16) u16 KL[208*KSTR];     // [j][d], rows >=200 zero
  __shared__ __align__(16) u16 VT[16*VSTR];      // [d][j], cols 200..207 zero
  const int b = blockIdx.x;
  const int h = blockIdx.y;
  const int t = threadIdx.x;
  const int w = t >> 6, L = t & 63;
  const int l16 = L & 15, lq = L >> 4;

  // zero only pad regions (disjoint from staged area -> race-free before barrier)
  if (t < 192) KL[200*KSTR + t] = 0;                       // rows 200..207, cols 0..23
  if (t < 128){ int d = t >> 3, c = t & 7; VT[d*VSTR + 200 + c] = 0; }

  // stage K rows + V transposed, PERMUTED BY RANK: row j <- agent old_action[j]
  if (t < AA){
    int a = oa[(size_t)b*AA + t];
    const u16* src = proj + ((size_t)(b*AA + a))*N3 + h*16;   // gK
    uint4 k0 = *(const uint4*)(src);
    uint4 k1 = *(const uint4*)(src + 8);
    *(uint4*)&KL[t*KSTR]     = k0;
    *(uint4*)&KL[t*KSTR + 8] = k1;
    const u16* sv = src + 128;                                // gV
    u16 d16[16];
    *(uint4*)(d16)   = *(const uint4*)(sv);
    *(uint4*)(d16+8) = *(const uint4*)(sv+8);
    #pragma unroll
    for (int d = 0; d < 16; ++d) VT[d*VSTR + t] = d16[d];
  }
  __syncthreads();

  u16* Qbase = qhg + (size_t)b*AA*DD + h*16;
  // hoisted diagonal-mask compares (j_local < i_local)
  const bool dm0 = (lq*4 + 0) < l16;
  const bool dm1 = (lq*4 + 1) < l16;
  const bool dm2 = (lq*4 + 2) < l16;
  const bool dm3 = (lq*4 + 3) < l16;

  if (w == 0){
    attn_tile<0>(KL, VT, Qbase, l16, lq, dm0, dm1, dm2, dm3);
    attn_tile<3>(KL, VT, Qbase, l16, lq, dm0, dm1, dm2, dm3);
  } else if (w == 1){
    attn_tile<1>(KL, VT, Qbase, l16, lq, dm0, dm1, dm2, dm3);
    attn_tile<2>(KL, VT, Qbase, l16, lq, dm0, dm1, dm2, dm3);
  } else if (w == 2){
    attn_tile<4>(KL, VT, Qbase, l16, lq, dm0, dm1, dm2, dm3);
    attn_tile<6>(KL, VT, Qbase, l16, lq, dm0, dm1, dm2, dm3);
    attn_tile<8>(KL, VT, Qbase, l16, lq, dm0, dm1, dm2, dm3);
    attn_tile<10>(KL, VT, Qbase, l16, lq, dm0, dm1, dm2, dm3);
    attn_tile<12>(KL, VT, Qbase, l16, lq, dm0, dm1, dm2, dm3);
  } else {
    attn_tile<5>(KL, VT, Qbase, l16, lq, dm0, dm1, dm2, dm3);
    attn_tile<7>(KL, VT, Qbase, l16, lq, dm0, dm1, dm2, dm3);
    attn_tile<9>(KL, VT, Qbase, l16, lq, dm0, dm1, dm2, dm3);
    attn_tile<11>(KL, VT, Qbase, l16, lq, dm0, dm1, dm2, dm3);
  }
}

// ---------------- K4: glimpse = heads @ W_out via MFMA -> proj cols [0..127] ----------------
__global__ __launch_bounds__(256) void k_glimpse_mfma(const u16* __restrict__ qhg,
                                                      const u16* __restrict__ WoT,
                                                      u16* __restrict__ proj){
  const int t = threadIdx.x;
  const int w = t >> 6, L = t & 63;
  const int l16 = L & 15, lq = L >> 4;
  const int m0 = blockIdx.x * 128;
  const int row0 = m0 + w*32;

  f32x4 acc[2][8] = {};
  const u16* Arow0 = qhg + (size_t)(row0 + l16)*DD;
  const u16* Arow1 = Arow0 + (size_t)16*DD;
  #pragma unroll
  for (int ks = 0; ks < 4; ++ks){
    int ko = ks*32 + lq*8;
    union { uint4 u; bf16x8 v; } a0, a1;
    a0.u = *(const uint4*)(Arow0 + ko);
    a1.u = *(const uint4*)(Arow1 + ko);
    #pragma unroll
    for (int nt = 0; nt < 8; ++nt){
      union { uint4 u; bf16x8 v; } bb;
      bb.u = *(const uint4*)(WoT + (size_t)(nt*16 + l16)*DD + ko);
      acc[0][nt] = __builtin_amdgcn_mfma_f32_16x16x32_bf16(a0.v, bb.v, acc[0][nt], 0, 0, 0);
      acc[1][nt] = __builtin_amdgcn_mfma_f32_16x16x32_bf16(a1.v, bb.v, acc[1][nt], 0, 0, 0);
    }
  }
  #pragma unroll
  for (int mt = 0; mt < 2; ++mt)
    #pragma unroll
    for (int r = 0; r < 4; ++r){
      int row = row0 + mt*16 + lq*4 + r;
      u16* dst = proj + (size_t)row*N3;
      #pragma unroll
      for (int nt = 0; nt < 8; ++nt)
        dst[nt*16 + l16] = f2bf(acc[mt][nt][r]);
    }
}

// ---------------- K5: MFMA logits: tanh -> mask -> log_softmax -> gather -> sum ----------------
__global__ __launch_bounds__(256) void k_logits(const u16* __restrict__ proj,
                                                const int* __restrict__ rank,
                                                const int* __restrict__ oa,
                                                float* __restrict__ outlps){
  __shared__ float red[4];
  const int b = blockIdx.x;
  const int t = threadIdx.x;
  const int w = t >> 6, L = t & 63;
  const int l16 = L & 15, lq = L >> 4;
  const float inv_sqrt_d = 0.08838834764831843f;  // 1/sqrt(128)

  const u16* Gbase  = proj + (size_t)b*AA*N3;       // glimpse cols [0..127]
  const u16* LKbase = Gbase + 256;                  // logit_K cols [256..383]

  int ra[13];
  #pragma unroll
  for (int at = 0; at < 13; ++at){
    int a = at*16 + l16;
    ra[at] = (a < AA) ? rank[b*AA + a] : -1;        // -1 => always masked
  }

  float lp_part = 0.f;

  for (int it = w; it < 13; it += 4){
    bf16x8 af[4];
    {
      const u16* arow = Gbase + (size_t)(it*16 + l16)*N3;
      #pragma unroll
      for (int kb = 0; kb < 4; ++kb){
        union { uint4 u; bf16x8 v; } tmp;
        tmp.u = *(const uint4*)(arow + kb*32 + lq*8);
        af[kb] = tmp.v;
      }
    }
    f32x4 S[13];
    #pragma unroll
    for (int at = 0; at < 13; ++at){
      const u16* brow = LKbase + (size_t)(at*16 + l16)*N3;
      f32x4 acc = {0.f,0.f,0.f,0.f};
      #pragma unroll
      for (int kb = 0; kb < 4; ++kb){
        union { uint4 u; bf16x8 v; } tmp;
        tmp.u = *(const uint4*)(brow + kb*32 + lq*8);
        acc = __builtin_amdgcn_mfma_f32_16x16x32_bf16(af[kb], tmp.v, acc, 0, 0, 0);
      }
      S[at] = acc;
    }
    #pragma unroll
    for (int at = 0; at < 13; ++at)
      #pragma unroll
      for (int r = 0; r < 4; ++r){
        int i = it*16 + lq*4 + r;
        float x = S[at][r] * inv_sqrt_d;
        float e = __expf(2.0f*x);
        float th = 1.0f - 2.0f/(e + 1.0f);
        S[at][r] = (ra[at] < i) ? -__builtin_inff() : 10.0f*th;
      }
    #pragma unroll
    for (int r = 0; r < 4; ++r){
      int i = it*16 + lq*4 + r;
      float m = S[0][r];
      #pragma unroll
      for (int at = 1; at < 13; ++at) m = fmaxf(m, S[at][r]);
      #pragma unroll
      for (int off = 1; off < 16; off <<= 1) m = fmaxf(m, __shfl_xor(m, off));
      float sum = 0.f;
      #pragma unroll
      for (int at = 0; at < 13; ++at) sum += __expf(S[at][r] - m);
      #pragma unroll
      for (int off = 1; off < 16; off <<= 1) sum += __shfl_xor(sum, off);
      if (i < AA){
        float lse = m + __logf(sum);
        int act = oa[b*AA + i];
        if ((act & 15) == l16){
          int at0 = act >> 4;
          #pragma unroll
          for (int at = 0; at < 13; ++at)
            if (at == at0) lp_part += S[at][r] - lse;
        }
      }
    }
  }
  #pragma unroll
  for (int off = 1; off < 64; off <<= 1) lp_part += __shfl_xor(lp_part, off);
  if (L == 0) red[w] = lp_part;
  __syncthreads();
  if (t == 0) outlps[b] = red[0] + red[1] + red[2] + red[3];
}

// ---------------- launch ----------------
extern "C" void kernel_launch(void* const* d_in, const int* in_sizes, int n_in,
                              void* d_out, int out_size, void* d_ws, size_t ws_size,
                              hipStream_t stream){
  const float* E  = (const float*)d_in[0];
  const int*   oa = (const int*)d_in[1];
  const float* Wp = (const float*)d_in[2];
  const float* Wn = (const float*)d_in[3];
  const float* Wf = (const float*)d_in[4];
  const float* Ws = (const float*)d_in[5];
  const float* Wo = (const float*)d_in[6];
  float* out = (float*)d_out;

  char* ws = (char*)d_ws;
  int*   rank   = (int*)ws;                     //   819,200 B
  float* fixedc = (float*)(ws + 819200);        //   524,288 B
  u16*   proj   = (u16*)(ws + 1343488);         // 157,286,400 B  [B][A][384] bf16
  u16*   qhg    = (u16*)(ws + 158629888);       //  52,428,800 B  [B][A][128] bf16
  u16*   WnT    = (u16*)(ws + 211058688);       //      98,304 B  [384][128] bf16
  u16*   WsT    = (u16*)(ws + 211156992);       //      32,768 B  [128][128] bf16
  u16*   WoT    = (u16*)(ws + 211189760);       //      32,768 B  [128][128] bf16
  // total workspace: 211,222,528 B

  k_act_rank<<<dim3((BB*AA)/256), 256, 0, stream>>>(oa, out, rank);
  k_prep<<<dim3(320), 256, 0, stream>>>(Wn, Ws, Wo, WnT, WsT, WoT);
  k_fixed<<<dim3(BB), 256, 0, stream>>>(E, Wf, fixedc);
  k_proj_mfma<<<dim3((BB*AA)/64), 256, 0, stream>>>(E, WnT, proj);
  k_query_mfma<<<dim3((BB*AA)/128), 256, 0, stream>>>(E, oa, Wp, WsT, fixedc, qhg);
  k_attn<<<dim3(BB, HH), 256, 0, stream>>>(proj, oa, qhg);
  k_glimpse_mfma<<<dim3((BB*AA)/128), 256, 0, stream>>>(qhg, WoT, proj);
  k_logits<<<dim3(BB), 256, 0, stream>>>(proj, rank, oa, out + BB*AA);
}

// Round 7
// 635.373 us; speedup vs baseline: 1.1438x; 1.1438x over previous
//
#include <hip/hip_runtime.h>
#include <cstdint>
#include <cstddef>

#define BB 1024
#define AA 200
#define DD 128
#define HH 8
#define N3 384

typedef unsigned short u16;
typedef unsigned int u32;
typedef __attribute__((ext_vector_type(8))) short bf16x8;
typedef __attribute__((ext_vector_type(4))) float f32x4;

__device__ __forceinline__ float bf2f(u16 v){ return __uint_as_float(((u32)v) << 16); }
__device__ __forceinline__ u16 f2bf(float f){
  u32 u = __float_as_uint(f);
  u32 r = u + 0x7fffu + ((u >> 16) & 1u);
  return (u16)(r >> 16);
}
// RNE pair pack (pure C)
__device__ __forceinline__ u32 pack2(float lo, float hi){
  return (u32)f2bf(lo) | ((u32)f2bf(hi) << 16);
}
// truncating pair pack (3 VALU ops) — used for P e-values only (round-0-verified)
__device__ __forceinline__ u32 pack2t(float lo, float hi){
  return (__float_as_uint(hi) & 0xFFFF0000u) | (__float_as_uint(lo) >> 16);
}
__device__ __forceinline__ bf16x8 pack8(float4 a, float4 b){
  bf16x8 o;
  o[0] = (short)f2bf(a.x); o[1] = (short)f2bf(a.y);
  o[2] = (short)f2bf(a.z); o[3] = (short)f2bf(a.w);
  o[4] = (short)f2bf(b.x); o[5] = (short)f2bf(b.y);
  o[6] = (short)f2bf(b.z); o[7] = (short)f2bf(b.w);
  return o;
}

// ---------------- K0: copy old_action to out (as float) + build rank ----------------
__global__ void k_act_rank(const int* __restrict__ oa, float* __restrict__ out0,
                           int* __restrict__ rank){
  int m = blockIdx.x * 256 + threadIdx.x;
  if (m >= BB*AA) return;
  int v = oa[m];
  out0[m] = (float)v;
  int b = m / AA;
  int j = m - b*AA;
  rank[b*AA + v] = j;
}

// ---------------- K0b: transpose+cast weights to bf16 [n][k] ----------------
__global__ void k_prep(const float* __restrict__ Wn, const float* __restrict__ Ws,
                       const float* __restrict__ Wo,
                       u16* __restrict__ WnT, u16* __restrict__ WsT,
                       u16* __restrict__ WoT){
  int idx = blockIdx.x * 256 + threadIdx.x;
  if (idx < 49152){                       // WnT: [384][128]
    int n = idx >> 7, k = idx & 127;
    WnT[idx] = f2bf(Wn[k*N3 + n]);
  } else if (idx < 65536){                // WsT: [128][128]
    int j = idx - 49152;
    int n = j >> 7, k = j & 127;
    WsT[j] = f2bf(Ws[k*DD + n]);
  } else if (idx < 81920){                // WoT: [128][128]
    int j = idx - 65536;
    int n = j >> 7, k = j & 127;
    WoT[j] = f2bf(Wo[k*DD + n]);
  }
}

// ---------------- K1: fixed_ctx = mean_a(E[b]) @ W_fixed ----------------
// 256 threads: two 100-row half-sums (halved dep chain, 2x TLP), LDS combine, GEMV.
__global__ void k_fixed(const float* __restrict__ E, const float* __restrict__ Wf,
                        float* __restrict__ fixedc){
  int b = blockIdx.x;
  int t = threadIdx.x;              // 256 threads
  int half = t >> 7, d = t & 127;
  __shared__ float ge[2][DD];
  const float* Eb = E + (size_t)b*AA*DD + (size_t)half*100*DD;
  float s = 0.f;
  #pragma unroll 4
  for (int a = 0; a < 100; ++a) s += Eb[a*DD + d];
  ge[half][d] = s;
  __syncthreads();
  if (t < DD){
    float acc = 0.f;
    for (int k = 0; k < DD; ++k){
      float gk = (ge[0][k] + ge[1][k]) * (1.0f/AA);
      acc = fmaf(gk, Wf[k*DD + t], acc);
    }
    fixedc[b*DD + t] = acc;
  }
}

// ---------------- K2a: proj = E @ W_node via MFMA, LDS-staged A ----------------
// Round-4 fragment math/stores kept; A-operand now staged once per block:
// 128x128 E tile -> bf16 in LDS (XOR-swizzled rows, G4: byte ^= (row&7)<<4),
// cvt off the per-wave critical path; each block covers all 384 n-cols in
// 3 sequential chunks so E is demanded from HBM exactly once.
__global__ __launch_bounds__(256) void k_proj_mfma(const float* __restrict__ E,
                                                   const u16* __restrict__ WnT,
                                                   u16* __restrict__ proj){
  __shared__ __align__(16) u16 EL[128*128];     // 32 KB bf16, swizzled
  const int t = threadIdx.x;
  const int w = t >> 6, L = t & 63;
  const int l16 = L & 15, lq = L >> 4;
  const int m0 = blockIdx.x * 128;

  // cooperative stage: 4096 float4, coalesced; 16 per thread
  const float4* Ef4 = (const float4*)(E + (size_t)m0*DD);
  #pragma unroll
  for (int i = 0; i < 16; ++i){
    int v = i*256 + t;                  // float4 index in 128x128 tile
    int row = v >> 5, c4 = v & 31;      // 32 float4 per row
    float4 f = Ef4[v];
    uint2 p; p.x = pack2(f.x, f.y); p.y = pack2(f.z, f.w);
    int byte_off = (row << 8) + ((c4 << 3) ^ ((row & 7) << 4));
    *(uint2*)((char*)EL + byte_off) = p;
  }
  __syncthreads();

  const int r0 = w*32 + l16;            // local A rows for mt=0 / mt=1
  const int r1 = r0 + 16;
  const int sw = (l16 & 7) << 4;        // row-XOR (mt offset 16 keeps row&7)

  #pragma unroll
  for (int c = 0; c < 3; ++c){
    const int n0 = c*128;
    f32x4 acc[2][8] = {};
    #pragma unroll
    for (int ks = 0; ks < 4; ++ks){
      const int kb = ks*64 + lq*16;     // byte col within row
      const int ko = ks*32 + lq*8;      // u16 col (for WnT)
      union { uint4 u; bf16x8 v; } a0, a1;
      a0.u = *(const uint4*)((const char*)EL + (r0 << 8) + (kb ^ sw));
      a1.u = *(const uint4*)((const char*)EL + (r1 << 8) + (kb ^ sw));
      #pragma unroll
      for (int nt = 0; nt < 8; ++nt){
        union { uint4 u; bf16x8 v; } bb;
        bb.u = *(const uint4*)(WnT + (size_t)(n0 + nt*16 + l16)*DD + ko);
        acc[0][nt] = __builtin_amdgcn_mfma_f32_16x16x32_bf16(a0.v, bb.v, acc[0][nt], 0, 0, 0);
        acc[1][nt] = __builtin_amdgcn_mfma_f32_16x16x32_bf16(a1.v, bb.v, acc[1][nt], 0, 0, 0);
      }
    }
    #pragma unroll
    for (int mt = 0; mt < 2; ++mt)
      #pragma unroll
      for (int r = 0; r < 4; ++r){
        int row = m0 + w*32 + mt*16 + lq*4 + r;
        u16* dst = proj + (size_t)row*N3 + n0;
        #pragma unroll
        for (int nt = 0; nt < 8; ++nt)
          dst[nt*16 + l16] = f2bf(acc[mt][nt][r]);
      }
  }
}

// ---------------- K2b: query = (fixed_ctx + gather(E,prev) @ W_step) * 0.25 via MFMA ----------------
// NOTE: 1/sqrt(dh)=0.25 folded into the stored query (qhg consumed only by k_attn QK^T).
__global__ __launch_bounds__(256) void k_query_mfma(const float* __restrict__ E,
                                                    const int* __restrict__ oa,
                                                    const float* __restrict__ Wp,
                                                    const u16* __restrict__ WsT,
                                                    const float* __restrict__ fixedc,
                                                    u16* __restrict__ qhg){
  const int t = threadIdx.x;
  const int w = t >> 6, L = t & 63;
  const int l16 = L & 15, lq = L >> 4;
  const int m0 = blockIdx.x * 128;
  const int row0 = m0 + w*32;

  const float* src[2];
  #pragma unroll
  for (int mt = 0; mt < 2; ++mt){
    int q = row0 + mt*16 + l16;
    int b = q / AA, i = q - b*AA;
    src[mt] = (i == 0) ? Wp : (E + (size_t)(b*AA + oa[b*AA + i - 1])*DD);
  }

  f32x4 acc[2][8] = {};
  #pragma unroll
  for (int ks = 0; ks < 4; ++ks){
    int ko = ks*32 + lq*8;
    bf16x8 a0 = pack8(*(const float4*)(src[0] + ko), *(const float4*)(src[0] + ko + 4));
    bf16x8 a1 = pack8(*(const float4*)(src[1] + ko), *(const float4*)(src[1] + ko + 4));
    #pragma unroll
    for (int nt = 0; nt < 8; ++nt){
      union { uint4 u; bf16x8 v; } bb;
      bb.u = *(const uint4*)(WsT + (size_t)(nt*16 + l16)*DD + ko);
      acc[0][nt] = __builtin_amdgcn_mfma_f32_16x16x32_bf16(a0, bb.v, acc[0][nt], 0, 0, 0);
      acc[1][nt] = __builtin_amdgcn_mfma_f32_16x16x32_bf16(a1, bb.v, acc[1][nt], 0, 0, 0);
    }
  }
  #pragma unroll
  for (int mt = 0; mt < 2; ++mt)
    #pragma unroll
    for (int r = 0; r < 4; ++r){
      int row = row0 + mt*16 + lq*4 + r;
      int b = row / AA;
      const float* fc = fixedc + (size_t)b*DD;
      u16* dst = qhg + (size_t)row*DD;
      #pragma unroll
      for (int nt = 0; nt < 8; ++nt)
        dst[nt*16 + l16] = f2bf((acc[mt][nt][r] + fc[nt*16 + l16]) * 0.25f);
    }
}

// ---------------- K3: MFMA attention, rank-permuted K/V (triangular mask) ----------------
// LDS row j holds K[old_action[j]] / V[old_action[j]]  (rank[old_action[j]] = j), so
// the revisit mask "rank[a] < i" becomes "j < i":
//   at-tile < it-tile  -> fully masked -> SKIPPED (never computed)
//   at-tile > it-tile  -> fully unmasked -> no mask ops at all
//   at == it (diagonal)-> mask iff (lq*4+r) < l16 (pure lane arith, hoisted compares)
//   at == 12           -> pad rows j>=200 masked via lq>=2
// S^T = mfma(K,Q): lane l16 = i, regs (k,r) hold j = at*16 + lq*4 + r.
// P^T packed on-the-fly (truncating bf16) feeds PV: H^T = V^T P^T.
// Per-wave STATIC tile schedule (compile-time indexing; weight 13-it):
//   w0:{0,3}=23  w1:{1,2}=23  w2:{4,6,8,10,12}=25  w3:{5,7,9,11}=20
#define KSTR 24    // u16 stride for KL rows (bank stagger)
#define VSTR 232   // u16 stride for VT rows
template<int IT>
__device__ __forceinline__ void attn_tile(const u16* KL, const u16* VT,
                                          u16* Qbase, int l16, int lq,
                                          bool dm0, bool dm1, bool dm2, bool dm3){
  constexpr int NT = 13 - IT;
  const int qi = IT*16 + l16;
  const float NEG_INF = -__builtin_inff();

  // B-frag: Q[i=l16][d = lq*4 + j] at elements j=0..3, elements 4..7 zero
  union { uint4 u; bf16x8 v; } qf8;
  qf8.u.x = 0; qf8.u.y = 0; qf8.u.z = 0; qf8.u.w = 0;
  if (qi < AA){
    uint2 q2 = *(const uint2*)(Qbase + (size_t)qi*DD + lq*4);
    qf8.u.x = q2.x; qf8.u.y = q2.y;
  }

  // S^T tiles for at = IT..12 only (at < IT fully masked -> skipped)
  f32x4 S[NT];
  #pragma unroll
  for (int k = 0; k < NT; ++k){
    const int at = IT + k;
    union { uint4 u; bf16x8 v; } kf8;
    uint2 k2 = *(const uint2*)&KL[(at*16 + l16)*KSTR + lq*4];
    kf8.u.x = k2.x; kf8.u.y = k2.y; kf8.u.z = 0; kf8.u.w = 0;
    f32x4 z = {0.f,0.f,0.f,0.f};
    S[k] = __builtin_amdgcn_mfma_f32_16x16x32_bf16(kf8.v, qf8.v, z, 0, 0, 0);
  }
  // diagonal mask (k==0): j < i  <=>  (lq*4+r) < l16
  S[0][0] = dm0 ? NEG_INF : S[0][0];
  S[0][1] = dm1 ? NEG_INF : S[0][1];
  S[0][2] = dm2 ? NEG_INF : S[0][2];
  S[0][3] = dm3 ? NEG_INF : S[0][3];
  // pad mask (at==12 tile is k==NT-1): j = 192 + lq*4 + r >= 200  <=>  lq >= 2
  if (lq >= 2){
    S[NT-1][0] = NEG_INF; S[NT-1][1] = NEG_INF;
    S[NT-1][2] = NEG_INF; S[NT-1][3] = NEG_INF;
  }
  // row max: within-lane + 2 shuffles; clamp so fully-masked pad rows give e=0 not NaN
  float m = fmaxf(fmaxf(S[0][0], S[0][1]), fmaxf(S[0][2], S[0][3]));
  #pragma unroll
  for (int k = 1; k < NT; ++k)
    m = fmaxf(m, fmaxf(fmaxf(S[k][0], S[k][1]), fmaxf(S[k][2], S[k][3])));
  m = fmaxf(m, __shfl_xor(m, 16));
  m = fmaxf(m, __shfl_xor(m, 32));
  m = fmaxf(m, -1e30f);
  // e = exp(S - m); 4 parallel sum chains
  float s0 = 0.f, s1 = 0.f, s2 = 0.f, s3 = 0.f;
  #pragma unroll
  for (int k = 0; k < NT; ++k){
    float e0 = __expf(S[k][0] - m);
    float e1 = __expf(S[k][1] - m);
    float e2 = __expf(S[k][2] - m);
    float e3 = __expf(S[k][3] - m);
    S[k][0] = e0; S[k][1] = e1; S[k][2] = e2; S[k][3] = e3;
    s0 += e0; s1 += e1; s2 += e2; s3 += e3;
  }
  float sum = (s0 + s1) + (s2 + s3);
  sum += __shfl_xor(sum, 16);
  sum += __shfl_xor(sum, 32);
  float inv = 1.0f / sum;
  // H^T = V^T P^T over unmasked j-tiles only
  f32x4 acc = {0.f,0.f,0.f,0.f};
  #pragma unroll
  for (int k = 0; k < NT; ++k){
    const int at = IT + k;
    union { uint4 u; bf16x8 v; } pa8, vb8;
    pa8.u.x = pack2t(S[k][0], S[k][1]);
    pa8.u.y = pack2t(S[k][2], S[k][3]);
    pa8.u.z = 0; pa8.u.w = 0;
    uint2 v2 = *(const uint2*)&VT[l16*VSTR + at*16 + lq*4];
    vb8.u.x = v2.x; vb8.u.y = v2.y; vb8.u.z = 0; vb8.u.w = 0;
    acc = __builtin_amdgcn_mfma_f32_16x16x32_bf16(vb8.v, pa8.v, acc, 0, 0, 0);
  }
  // D: lane holds col i = l16, rows d = lq*4 + r -> H[i][d], packed 8B store (RNE)
  if (qi < AA){
    uint2 ov;
    ov.x = pack2(acc[0]*inv, acc[1]*inv);
    ov.y = pack2(acc[2]*inv, acc[3]*inv);
    *(uint2*)(Qbase + (size_t)qi*DD + lq*4) = ov;
  }
}

// 1-D grid 8192 with XCD co-location: all 8 heads of a batch b land on the
// same XCD (idx&7), temporally adjacent -> shared K/V cache lines hit in L2.
__global__ __launch_bounds__(256) void k_attn(const u16* __restrict__ proj,
                                              const int* __restrict__ oa,
                                              u16* __restrict__ qhg){
  __shared__ __align__(16) u16 KL[208*KSTR];     // [j][d], rows >=200 zero
  __shared__ __align__(16) u16 VT[16*VSTR];      // [d][j], cols 200..207 zero
  const int idx = blockIdx.x;
  const int b = ((idx & 7) << 7) + (idx >> 6);   // xcd*128 + seq
  const int h = (idx >> 3) & 7;
  const int t = threadIdx.x;
  const int w = t >> 6, L = t & 63;
  const int l16 = L & 15, lq = L >> 4;

  // zero only pad regions (disjoint from staged area -> race-free before barrier)
  if (t < 192) KL[200*KSTR + t] = 0;                       // rows 200..207, cols 0..23
  if (t < 128){ int d = t >> 3, c = t & 7; VT[d*VSTR + 200 + c] = 0; }

  // stage K rows + V transposed, PERMUTED BY RANK: row j <- agent old_action[j]
  if (t < AA){
    int a = oa[(size_t)b*AA + t];
    const u16* src = proj + ((size_t)(b*AA + a))*N3 + h*16;   // gK
    uint4 k0 = *(const uint4*)(src);
    uint4 k1 = *(const uint4*)(src + 8);
    *(uint4*)&KL[t*KSTR]     = k0;
    *(uint4*)&KL[t*KSTR + 8] = k1;
    const u16* sv = src + 128;                                // gV
    u16 d16[16];
    *(uint4*)(d16)   = *(const uint4*)(sv);
    *(uint4*)(d16+8) = *(const uint4*)(sv+8);
    #pragma unroll
    for (int d = 0; d < 16; ++d) VT[d*VSTR + t] = d16[d];
  }
  __syncthreads();

  u16* Qbase = qhg + (size_t)b*AA*DD + h*16;
  // hoisted diagonal-mask compares (j_local < i_local)
  const bool dm0 = (lq*4 + 0) < l16;
  const bool dm1 = (lq*4 + 1) < l16;
  const bool dm2 = (lq*4 + 2) < l16;
  const bool dm3 = (lq*4 + 3) < l16;

  if (w == 0){
    attn_tile<0>(KL, VT, Qbase, l16, lq, dm0, dm1, dm2, dm3);
    attn_tile<3>(KL, VT, Qbase, l16, lq, dm0, dm1, dm2, dm3);
  } else if (w == 1){
    attn_tile<1>(KL, VT, Qbase, l16, lq, dm0, dm1, dm2, dm3);
    attn_tile<2>(KL, VT, Qbase, l16, lq, dm0, dm1, dm2, dm3);
  } else if (w == 2){
    attn_tile<4>(KL, VT, Qbase, l16, lq, dm0, dm1, dm2, dm3);
    attn_tile<6>(KL, VT, Qbase, l16, lq, dm0, dm1, dm2, dm3);
    attn_tile<8>(KL, VT, Qbase, l16, lq, dm0, dm1, dm2, dm3);
    attn_tile<10>(KL, VT, Qbase, l16, lq, dm0, dm1, dm2, dm3);
    attn_tile<12>(KL, VT, Qbase, l16, lq, dm0, dm1, dm2, dm3);
  } else {
    attn_tile<5>(KL, VT, Qbase, l16, lq, dm0, dm1, dm2, dm3);
    attn_tile<7>(KL, VT, Qbase, l16, lq, dm0, dm1, dm2, dm3);
    attn_tile<9>(KL, VT, Qbase, l16, lq, dm0, dm1, dm2, dm3);
    attn_tile<11>(KL, VT, Qbase, l16, lq, dm0, dm1, dm2, dm3);
  }
}

// ---------------- K4: glimpse = heads @ W_out via MFMA -> proj cols [0..127] ----------------
__global__ __launch_bounds__(256) void k_glimpse_mfma(const u16* __restrict__ qhg,
                                                      const u16* __restrict__ WoT,
                                                      u16* __restrict__ proj){
  const int t = threadIdx.x;
  const int w = t >> 6, L = t & 63;
  const int l16 = L & 15, lq = L >> 4;
  const int m0 = blockIdx.x * 128;
  const int row0 = m0 + w*32;

  f32x4 acc[2][8] = {};
  const u16* Arow0 = qhg + (size_t)(row0 + l16)*DD;
  const u16* Arow1 = Arow0 + (size_t)16*DD;
  #pragma unroll
  for (int ks = 0; ks < 4; ++ks){
    int ko = ks*32 + lq*8;
    union { uint4 u; bf16x8 v; } a0, a1;
    a0.u = *(const uint4*)(Arow0 + ko);
    a1.u = *(const uint4*)(Arow1 + ko);
    #pragma unroll
    for (int nt = 0; nt < 8; ++nt){
      union { uint4 u; bf16x8 v; } bb;
      bb.u = *(const uint4*)(WoT + (size_t)(nt*16 + l16)*DD + ko);
      acc[0][nt] = __builtin_amdgcn_mfma_f32_16x16x32_bf16(a0.v, bb.v, acc[0][nt], 0, 0, 0);
      acc[1][nt] = __builtin_amdgcn_mfma_f32_16x16x32_bf16(a1.v, bb.v, acc[1][nt], 0, 0, 0);
    }
  }
  #pragma unroll
  for (int mt = 0; mt < 2; ++mt)
    #pragma unroll
    for (int r = 0; r < 4; ++r){
      int row = row0 + mt*16 + lq*4 + r;
      u16* dst = proj + (size_t)row*N3;
      #pragma unroll
      for (int nt = 0; nt < 8; ++nt)
        dst[nt*16 + l16] = f2bf(acc[mt][nt][r]);
    }
}

// ---------------- K5: MFMA logits: tanh -> mask -> log_softmax -> gather -> sum ----------------
__global__ __launch_bounds__(256) void k_logits(const u16* __restrict__ proj,
                                                const int* __restrict__ rank,
                                                const int* __restrict__ oa,
                                                float* __restrict__ outlps){
  __shared__ float red[4];
  const int b = blockIdx.x;
  const int t = threadIdx.x;
  const int w = t >> 6, L = t & 63;
  const int l16 = L & 15, lq = L >> 4;
  const float inv_sqrt_d = 0.08838834764831843f;  // 1/sqrt(128)

  const u16* Gbase  = proj + (size_t)b*AA*N3;       // glimpse cols [0..127]
  const u16* LKbase = Gbase + 256;                  // logit_K cols [256..383]

  int ra[13];
  #pragma unroll
  for (int at = 0; at < 13; ++at){
    int a = at*16 + l16;
    ra[at] = (a < AA) ? rank[b*AA + a] : -1;        // -1 => always masked
  }

  float lp_part = 0.f;

  for (int it = w; it < 13; it += 4){
    bf16x8 af[4];
    {
      const u16* arow = Gbase + (size_t)(it*16 + l16)*N3;
      #pragma unroll
      for (int kb = 0; kb < 4; ++kb){
        union { uint4 u; bf16x8 v; } tmp;
        tmp.u = *(const uint4*)(arow + kb*32 + lq*8);
        af[kb] = tmp.v;
      }
    }
    f32x4 S[13];
    #pragma unroll
    for (int at = 0; at < 13; ++at){
      const u16* brow = LKbase + (size_t)(at*16 + l16)*N3;
      f32x4 acc = {0.f,0.f,0.f,0.f};
      #pragma unroll
      for (int kb = 0; kb < 4; ++kb){
        union { uint4 u; bf16x8 v; } tmp;
        tmp.u = *(const uint4*)(brow + kb*32 + lq*8);
        acc = __builtin_amdgcn_mfma_f32_16x16x32_bf16(af[kb], tmp.v, acc, 0, 0, 0);
      }
      S[at] = acc;
    }
    #pragma unroll
    for (int at = 0; at < 13; ++at)
      #pragma unroll
      for (int r = 0; r < 4; ++r){
        int i = it*16 + lq*4 + r;
        float x = S[at][r] * inv_sqrt_d;
        float e = __expf(2.0f*x);
        float th = 1.0f - 2.0f/(e + 1.0f);
        S[at][r] = (ra[at] < i) ? -__builtin_inff() : 10.0f*th;
      }
    #pragma unroll
    for (int r = 0; r < 4; ++r){
      int i = it*16 + lq*4 + r;
      float m = S[0][r];
      #pragma unroll
      for (int at = 1; at < 13; ++at) m = fmaxf(m, S[at][r]);
      #pragma unroll
      for (int off = 1; off < 16; off <<= 1) m = fmaxf(m, __shfl_xor(m, off));
      float sum = 0.f;
      #pragma unroll
      for (int at = 0; at < 13; ++at) sum += __expf(S[at][r] - m);
      #pragma unroll
      for (int off = 1; off < 16; off <<= 1) sum += __shfl_xor(sum, off);
      if (i < AA){
        float lse = m + __logf(sum);
        int act = oa[b*AA + i];
        if ((act & 15) == l16){
          int at0 = act >> 4;
          #pragma unroll
          for (int at = 0; at < 13; ++at)
            if (at == at0) lp_part += S[at][r] - lse;
        }
      }
    }
  }
  #pragma unroll
  for (int off = 1; off < 64; off <<= 1) lp_part += __shfl_xor(lp_part, off);
  if (L == 0) red[w] = lp_part;
  __syncthreads();
  if (t == 0) outlps[b] = red[0] + red[1] + red[2] + red[3];
}

// ---------------- launch ----------------
extern "C" void kernel_launch(void* const* d_in, const int* in_sizes, int n_in,
                              void* d_out, int out_size, void* d_ws, size_t ws_size,
                              hipStream_t stream){
  const float* E  = (const float*)d_in[0];
  const int*   oa = (const int*)d_in[1];
  const float* Wp = (const float*)d_in[2];
  const float* Wn = (const float*)d_in[3];
  const float* Wf = (const float*)d_in[4];
  const float* Ws = (const float*)d_in[5];
  const float* Wo = (const float*)d_in[6];
  float* out = (float*)d_out;

  char* ws = (char*)d_ws;
  int*   rank   = (int*)ws;                     //   819,200 B
  float* fixedc = (float*)(ws + 819200);        //   524,288 B
  u16*   proj   = (u16*)(ws + 1343488);         // 157,286,400 B  [B][A][384] bf16
  u16*   qhg    = (u16*)(ws + 158629888);       //  52,428,800 B  [B][A][128] bf16
  u16*   WnT    = (u16*)(ws + 211058688);       //      98,304 B  [384][128] bf16
  u16*   WsT    = (u16*)(ws + 211156992);       //      32,768 B  [128][128] bf16
  u16*   WoT    = (u16*)(ws + 211189760);       //      32,768 B  [128][128] bf16
  // total workspace: 211,222,528 B

  k_act_rank<<<dim3((BB*AA)/256), 256, 0, stream>>>(oa, out, rank);
  k_prep<<<dim3(320), 256, 0, stream>>>(Wn, Ws, Wo, WnT, WsT, WoT);
  k_fixed<<<dim3(BB), 256, 0, stream>>>(E, Wf, fixedc);
  k_proj_mfma<<<dim3((BB*AA)/128), 256, 0, stream>>>(E, WnT, proj);
  k_query_mfma<<<dim3((BB*AA)/128), 256, 0, stream>>>(E, oa, Wp, WsT, fixedc, qhg);
  k_attn<<<dim3(BB*HH), 256, 0, stream>>>(proj, oa, qhg);
  k_glimpse_mfma<<<dim3((BB*AA)/128), 256, 0, stream>>>(qhg, WoT, proj);
  k_logits<<<dim3(BB), 256, 0, stream>>>(proj, rank, oa, out + BB*AA);
}